// Round 19
// baseline (3703.733 us; speedup 1.0000x reference)
//
#include <hip/hip_runtime.h>
#include <hip/hip_bf16.h>

typedef unsigned short u16;
typedef short bfrag __attribute__((ext_vector_type(8)));   // 8 bf16 operand frag
typedef float f32x4 __attribute__((ext_vector_type(4)));   // MFMA accumulator

#define L_LAYERS 12
#define BATCH 32
#define NTOK 576
#define DMODEL 768
#define NHEAD 12
#define DHEAD 64
#define BN_ROWS (BATCH * NTOK)   // 18432
#define QKV_N (3 * DMODEL)       // 2304

__device__ __forceinline__ u16 f2bf(float f) {
    __hip_bfloat16 h = __float2bfloat16(f);   // HW RNE convert
    return *reinterpret_cast<u16*>(&h);
}

__device__ __forceinline__ void gload_lds16(const void* g, void* l) {
    __builtin_amdgcn_global_load_lds(
        (const __attribute__((address_space(1))) void*)g,
        (__attribute__((address_space(3))) void*)l, 16, 0, 0);
}

// ---------------- transpose + fp32->bf16 cast: src[R][C] -> dst[C][R], per-layer via z ----------------
__global__ __launch_bounds__(256) void transpose_cast_kernel(
        const float* __restrict__ src, u16* __restrict__ dst, int R, int C) {
    __shared__ u16 tile[64][65];
    size_t loff = (size_t)blockIdx.z * R * C;
    src += loff;
    dst += loff;
    int c0 = blockIdx.x * 64, r0 = blockIdx.y * 64;
    int tid = threadIdx.x;
    for (int i = tid; i < 4096; i += 256) {
        int rr = i >> 6, cc = i & 63;
        tile[rr][cc] = f2bf(src[(size_t)(r0 + rr) * C + c0 + cc]);
    }
    __syncthreads();
    for (int i = tid; i < 4096; i += 256) {
        int cc = i >> 6, rr = i & 63;
        dst[(size_t)(c0 + cc) * R + r0 + rr] = tile[rr][cc];
    }
}

// ---------------- LayerNorm: fp32 z row -> bf16 out row (one row per wave) ----------------
__global__ __launch_bounds__(256) void ln_kernel(
        const float* __restrict__ z, const float* __restrict__ g,
        const float* __restrict__ b, u16* __restrict__ out) {
    int w = threadIdx.x >> 6, lane = threadIdx.x & 63;
    int row = blockIdx.x * 4 + w;
    const float* zr = z + (size_t)row * DMODEL;
    float4 v[3];
    float sum = 0.f, sq = 0.f;
#pragma unroll
    for (int c = 0; c < 3; ++c) {
        v[c] = *(const float4*)(zr + c * 256 + lane * 4);
        sum += v[c].x + v[c].y + v[c].z + v[c].w;
        sq  += v[c].x * v[c].x + v[c].y * v[c].y + v[c].z * v[c].z + v[c].w * v[c].w;
    }
#pragma unroll
    for (int m = 1; m < 64; m <<= 1) {
        sum += __shfl_xor(sum, m);
        sq  += __shfl_xor(sq, m);
    }
    float mean = sum * (1.0f / DMODEL);
    float var  = sq * (1.0f / DMODEL) - mean * mean;
    float inv  = 1.0f / sqrtf(var + 1e-5f);
    u16* orow = out + (size_t)row * DMODEL;
#pragma unroll
    for (int c = 0; c < 3; ++c) {
        int col = c * 256 + lane * 4;
        float4 gg = *(const float4*)(g + col);
        float4 bb = *(const float4*)(b + col);
        ushort4 u;
        u.x = f2bf((v[c].x - mean) * inv * gg.x + bb.x);
        u.y = f2bf((v[c].y - mean) * inv * gg.y + bb.y);
        u.z = f2bf((v[c].z - mean) * inv * gg.z + bb.z);
        u.w = f2bf((v[c].w - mean) * inv * gg.w + bb.w);
        *(ushort4*)(orow + col) = u;
    }
}

// ---------------- bf16 MFMA GEMM: 128(M)x256(N) block, 256 threads / 4 waves ----------------
// Each wave owns the FULL 128-row M panel x 64 cols: af[8] x bfv[4] -> 32 MFMA per
// K-step from 12 ds_read_b128 (0.375 reads/MFMA vs 0.5 before) — attacks the LDS
// read-BW bound. R18's T4 pipeline kept: 3 LDS buffers (72KB -> 2 blocks/CU), loads
// 2 K-steps ahead, counted s_waitcnt vmcnt(6) + ONE raw s_barrier per K-step.
// T2 XOR slot-swizzle kept (conflicts==0). T5 setprio around MFMA cluster.
// FIFO ledger: stage()=6 loads; at each barrier exactly next-step's 6 outstanding.
// NOTE: plain __launch_bounds__(256) — min-waves clause spills accumulators (R10).
template<int MODE>
__global__ __launch_bounds__(256) void gemm_kernel(
        const u16* __restrict__ A, const u16* __restrict__ Bt,
        int M, int N, int K,
        u16* __restrict__ obf, const float* __restrict__ bias, float* __restrict__ zres) {
    __shared__ __attribute__((aligned(16))) u16 As[3][128 * 32];   // 8KB per buf
    __shared__ __attribute__((aligned(16))) u16 Bs[3][256 * 32];   // 16KB per buf
    int tid = threadIdx.x;
    int lane = tid & 63, w = tid >> 6;        // w 0..3 (wave owns cols w*64..+63)
    int r = lane & 15, gq = lane >> 4;

    // XCD-aware bijective swizzle (nwg % 8 == 0 for all our launches)
    int nwg = gridDim.x * gridDim.y;
    int lin = blockIdx.y * gridDim.x + blockIdx.x;
    int swz = (lin & 7) * (nwg >> 3) + (lin >> 3);
    int bx = swz % gridDim.x, by = swz / gridDim.x;
    int m0 = by * 128, n0 = bx * 256;

    int srow = tid >> 2;          // 0..63 (4 lanes per row)
    // T2 swizzle, stage side: lane's k-segment = slot ^ ((srow>>1)&3)
    int sseg = (((tid & 3) ^ ((tid >> 3) & 3))) * 8;     // u16 col offset (pre-swizzled)
    const u16* aSrc = A  + (size_t)(m0 + srow) * K + sseg;
    const u16* bSrc = Bt + (size_t)(n0 + srow) * K + sseg;

    // T2 swizzle, read side (row bits: wr/mi/ni*16 all ≡0 mod 4 after >>1)
    int rslot = (gq ^ ((r >> 1) & 3)) * 8;               // u16 offset within row

    f32x4 acc[8][4];
#pragma unroll
    for (int mi = 0; mi < 8; ++mi)
#pragma unroll
        for (int ni = 0; ni < 4; ++ni)
            acc[mi][ni] = (f32x4){0.f, 0.f, 0.f, 0.f};

    // stage K-step kt into buffer sb: 6 gload_lds per thread (A rows 0-63,64-127;
    // B rows 0-63,64-127,128-191,192-255), LDS dest wave-linear
    auto stage = [&](int kt, int sb) {
        int o = kt << 5;
        gload_lds16(aSrc + o,                      &As[sb][w * 512]);
        gload_lds16(aSrc + (size_t)64 * K + o,     &As[sb][2048 + w * 512]);
        gload_lds16(bSrc + o,                      &Bs[sb][w * 512]);
        gload_lds16(bSrc + (size_t)64 * K + o,     &Bs[sb][2048 + w * 512]);
        gload_lds16(bSrc + (size_t)128 * K + o,    &Bs[sb][4096 + w * 512]);
        gload_lds16(bSrc + (size_t)192 * K + o,    &Bs[sb][6144 + w * 512]);
    };

    int T = K >> 5;
    // prologue: issue t=0 and t=1; wait t=0 landed (t=1's 6 may stay in flight)
    stage(0, 0);
    stage(1, 1);
    asm volatile("s_waitcnt vmcnt(6)" ::: "memory");
    __builtin_amdgcn_s_barrier();
    asm volatile("" ::: "memory");

    int cb = 0, sb = 2;   // read buffer, stage buffer (rotating mod 3)
    for (int t = 0; t < T; ++t) {
        bfrag af[8], bfv[4];
#pragma unroll
        for (int mi = 0; mi < 8; ++mi)
            af[mi] = *(const bfrag*)(&As[cb][(mi * 16 + r) * 32 + rslot]);
#pragma unroll
        for (int ni = 0; ni < 4; ++ni)
            bfv[ni] = *(const bfrag*)(&Bs[cb][(w * 64 + ni * 16 + r) * 32 + rslot]);

        bool more = (t + 2) < T;
        if (more) stage(t + 2, sb);

        __builtin_amdgcn_s_setprio(1);
#pragma unroll
        for (int mi = 0; mi < 8; ++mi)
#pragma unroll
            for (int ni = 0; ni < 4; ++ni)
                acc[mi][ni] = __builtin_amdgcn_mfma_f32_16x16x32_bf16(af[mi], bfv[ni], acc[mi][ni], 0, 0, 0);
        __builtin_amdgcn_s_setprio(0);

        if (more) asm volatile("s_waitcnt vmcnt(6)" ::: "memory");
        else      asm volatile("s_waitcnt vmcnt(0)" ::: "memory");
        asm volatile("" ::: "memory");
        __builtin_amdgcn_s_barrier();          // publish buf for t+1
        __builtin_amdgcn_sched_barrier(0);
        asm volatile("" ::: "memory");

        cb = (cb == 2) ? 0 : cb + 1;
        sb = (sb == 2) ? 0 : sb + 1;
    }

#pragma unroll
    for (int mi = 0; mi < 8; ++mi) {
#pragma unroll
        for (int ni = 0; ni < 4; ++ni) {
            int col = n0 + w * 64 + ni * 16 + r;
#pragma unroll
            for (int j = 0; j < 4; ++j) {
                int row = m0 + mi * 16 + gq * 4 + j;
                if (MODE == 0) {
                    obf[(size_t)row * N + col] = f2bf(acc[mi][ni][j]);
                } else {
                    zres[(size_t)row * N + col] += acc[mi][ni][j] + bias[col];
                }
            }
        }
    }
}

// ---------------- V transpose: qkv V-part [key][dh] -> vT [b][h][dh][key] ----------------
__global__ __launch_bounds__(256) void vtrans_kernel(
        const u16* __restrict__ qkv, u16* __restrict__ vT) {
    __shared__ u16 tile[64][65];
    int kt = blockIdx.x, h = blockIdx.y, b = blockIdx.z;
    int tid = threadIdx.x;
    int k0 = kt * 64;
    const u16* src = qkv + (size_t)(b * NTOK + k0) * QKV_N + h * 192 + 128;
    for (int i = tid; i < 4096; i += 256) {
        int rr = i >> 6, cc = i & 63;
        tile[rr][cc] = src[(size_t)rr * QKV_N + cc];
    }
    __syncthreads();
    u16* dst = vT + (size_t)(b * NHEAD + h) * DHEAD * NTOK + k0;
    for (int i = tid; i < 4096; i += 256) {
        int dh = i >> 6, kk = i & 63;
        dst[(size_t)dh * NTOK + kk] = tile[kk][dh];
    }
}

// ---------------- flash attention: 12 waves x 16 q-rows (QBLK=192, 576=3x192 exact).
//   K/V staged via coalesced global_load_lds (dbuf, XOR slot-swizzled source);
//   swapped-operand QK^T, in-lane softmax (max3 tree) with T13 defer-max, cvt_pk P2,
//   MFMA ones-row denominator, T5 setprio, ONE barrier per chunk.
//   1152 blocks = 8 XCDs x 48 groups x 3 q-tiles (bijective).
#define KC 64
#define NCHUNK 9
#define SM_C 0.18033688f   // 0.125 * log2(e)
#define DEFER_THR 44.3614f // 8 / SM_C: skip rescale while P bounded by 2^8
__global__ __launch_bounds__(768) void attn_kernel(
        const u16* __restrict__ qkv, const u16* __restrict__ vT, float* __restrict__ z) {
    __shared__ __attribute__((aligned(16))) u16 Kst[2][KC * 64];        // [key][dh-slot]  16KB
    __shared__ __attribute__((aligned(16))) u16 Vst[2][DHEAD * KC];     // [dh][key-slot]  16KB
    __shared__ __attribute__((aligned(16))) unsigned P2[12][16][36];    // [wave][q][keypair+pad] 27KB
    int i = blockIdx.x;
    int slot = i >> 3;            // 0..143
    int qt = slot % 3;
    int g = (i & 7) * 48 + slot / 3;
    int h = g % NHEAD, b = g / NHEAD;
    int tid = threadIdx.x, lane = tid & 63, w = tid >> 6;   // w 0..11
    int r = lane & 15, gq = lane >> 4;
    int q0 = qt * 192 + w * 16;

    // Q fragments (B-operand of swapped QK^T): lane holds Q[q=q0+r][dh=gq*8..+7]
    const u16* qbase = qkv + (size_t)(b * NTOK + q0 + r) * QKV_N + h * 192;
    bfrag qf0 = *(const bfrag*)(qbase + gq * 8);
    bfrag qf1 = *(const bfrag*)(qbase + 32 + gq * 8);

    // staging lane geometry: each call covers 8 rows (8 lanes x 16B per row)
    int lrow = lane >> 3;                    // 0..7
    int sslot = (lane & 7) ^ lrow;           // XOR swizzle (row&7 == lrow)
    const u16* ksrc = qkv + (size_t)(b * NTOK + lrow) * QKV_N + h * 192 + 64 + sslot * 8;
    const u16* vsrc = vT + ((size_t)(b * NHEAD + h) * DHEAD + lrow) * NTOK + sslot * 8;

    float* zb = z + (size_t)(b * NTOK + q0) * DMODEL + h * DHEAD;

    bfrag ones;
#pragma unroll
    for (int q = 0; q < 8; ++q) ones[q] = (short)0x3F80;   // bf16 1.0 x8

    float mrun = -1e30f;
    f32x4 o[4], lacc;
#pragma unroll
    for (int ni = 0; ni < 4; ++ni) o[ni] = (f32x4){0.f, 0.f, 0.f, 0.f};
    lacc = (f32x4){0.f, 0.f, 0.f, 0.f};

    // stage chunk c into buffer bf: 16 segments (K rows = c2 0..7, V rows = c2 8..15),
    // wave w takes c2 = w and w+12 (<16); wave-uniform branch
    auto stage = [&](int c, int bf) {
#pragma unroll
        for (int k = 0; k < 2; ++k) {
            int c2 = w + 12 * k;
            if (c2 < 16) {
                if (c2 < 8)
                    gload_lds16(ksrc + (size_t)(c * KC + c2 * 8) * QKV_N,
                                &Kst[bf][(c2 * 8) * 64]);
                else
                    gload_lds16(vsrc + (size_t)((c2 - 8) * 8) * NTOK + c * KC,
                                &Vst[bf][((c2 - 8) * 8) * 64]);
            }
        }
    };

    // prologue: stage chunk 0 into buf 0
    stage(0, 0);
    __syncthreads();

#pragma unroll
    for (int c = 0; c < NCHUNK; ++c) {
        int cur = c & 1;
        if (c + 1 < NCHUNK) stage(c + 1, cur ^ 1);

        // S^T chunk = (K @ Q^T): s[kc][j] = S[key = c*64+kc*16+gq*4+j][q = q0+r]
        // K frags from swizzled LDS: row kc*16+r, want slot gq -> stored gq^(r&7).
        f32x4 s[4];
#pragma unroll
        for (int kc = 0; kc < 4; ++kc) s[kc] = (f32x4){0.f, 0.f, 0.f, 0.f};
        int s0 = gq ^ (r & 7);
        __builtin_amdgcn_s_setprio(1);
#pragma unroll
        for (int kc = 0; kc < 4; ++kc) {
            const u16* kf = &Kst[cur][(kc * 16 + r) * 64];
            bfrag k0 = *(const bfrag*)(kf + s0 * 8);
            bfrag k1 = *(const bfrag*)(kf + (s0 ^ 4) * 8);
            s[kc] = __builtin_amdgcn_mfma_f32_16x16x32_bf16(k0, qf0, s[kc], 0, 0, 0);
            s[kc] = __builtin_amdgcn_mfma_f32_16x16x32_bf16(k1, qf1, s[kc], 0, 0, 0);
        }
        __builtin_amdgcn_s_setprio(0);

        // chunk max for q = q0+r: max3-friendly tree over 16 + 2 cross-gq shfl
        float m0a = fmaxf(fmaxf(s[0][0], s[0][1]), s[0][2]);
        float m0b = fmaxf(fmaxf(s[0][3], s[1][0]), s[1][1]);
        float m0c = fmaxf(fmaxf(s[1][2], s[1][3]), s[2][0]);
        float m0d = fmaxf(fmaxf(s[2][1], s[2][2]), s[2][3]);
        float m0e = fmaxf(fmaxf(s[3][0], s[3][1]), s[3][2]);
        float cm  = fmaxf(fmaxf(m0a, m0b), fmaxf(fmaxf(m0c, m0d), fmaxf(m0e, s[3][3])));
        cm = fmaxf(cm, __shfl_xor(cm, 16));
        cm = fmaxf(cm, __shfl_xor(cm, 32));

        // T13 defer-max: keep old max while growth <= 8/SM_C (P bounded by 2^8; exact
        // after final O/l normalize). Rescale only on real growth.
        bool need = !__all(cm <= mrun + DEFER_THR);
        float nm = need ? fmaxf(mrun, cm) : mrun;
        float nmC = nm * SM_C;
#pragma unroll
        for (int kc = 0; kc < 4; ++kc)
#pragma unroll
            for (int j = 0; j < 4; ++j)
                s[kc][j] = exp2f(s[kc][j] * SM_C - nmC);
        if (need) {
            float fac = exp2f((mrun - nm) * SM_C);
            mrun = nm;
#pragma unroll
            for (int ni = 0; ni < 4; ++ni)
#pragma unroll
                for (int j = 0; j < 4; ++j) o[ni][j] *= fac;
#pragma unroll
            for (int j = 0; j < 4; ++j) lacc[j] *= fac;
        }

        // pack P to bf16 pairs -> per-wave LDS P2 (P row per q, contiguous keys)
#pragma unroll
        for (int kc = 0; kc < 4; ++kc)
#pragma unroll
            for (int X = 0; X < 2; ++X) {
                unsigned pk;
                asm("v_cvt_pk_bf16_f32 %0, %1, %2" : "=v"(pk) : "v"(s[kc][2 * X]), "v"(s[kc][2 * X + 1]));
                P2[w][r][kc * 8 + gq * 2 + X] = pk;
            }

        // O^T += V^T @ P^T ; denominator l += 1^T @ P^T (ones-row MFMA replaces the
        // VALU sum chain — l computed from the same bf16 P that PV consumes).
        __builtin_amdgcn_s_setprio(1);
#pragma unroll
        for (int ks = 0; ks < 2; ++ks) {
            bfrag pf = *(const bfrag*)(&P2[w][r][ks * 16 + gq * 4]);
            int vs = (ks * 4 + gq) ^ (r & 7);
#pragma unroll
            for (int ni = 0; ni < 4; ++ni) {
                bfrag vf = *(const bfrag*)(&Vst[cur][(ni * 16 + r) * 64 + vs * 8]);
                o[ni] = __builtin_amdgcn_mfma_f32_16x16x32_bf16(vf, pf, o[ni], 0, 0, 0);
            }
            lacc = __builtin_amdgcn_mfma_f32_16x16x32_bf16(ones, pf, lacc, 0, 0, 0);
        }
        __builtin_amdgcn_s_setprio(0);
        __syncthreads();   // all waves done with Kst/Vst[cur]; prefetch landed
    }

    // z += O / l : lane (gq,r) holds O[q=r][dh = ni*16 + gq*4 + j]  (float4 RMW, disjoint)
    float inv = 1.0f / lacc[0];
#pragma unroll
    for (int ni = 0; ni < 4; ++ni) {
        float* p = zb + (size_t)r * DMODEL + ni * 16 + gq * 4;
        float4 t = *(float4*)p;
        t.x += o[ni][0] * inv;
        t.y += o[ni][1] * inv;
        t.z += o[ni][2] * inv;
        t.w += o[ni][3] * inv;
        *(float4*)p = t;
    }
}

extern "C" void kernel_launch(void* const* d_in, const int* in_sizes, int n_in,
                              void* d_out, int out_size, void* d_ws, size_t ws_size,
                              hipStream_t stream) {
    const float* z_in  = (const float*)d_in[0];
    const float* Wqkv  = (const float*)d_in[1];
    const float* ln1_g = (const float*)d_in[2];
    const float* ln1_b = (const float*)d_in[3];
    const float* Wmlp  = (const float*)d_in[4];
    const float* bmlp  = (const float*)d_in[5];
    const float* ln2_g = (const float*)d_in[6];
    const float* ln2_b = (const float*)d_in[7];
    float* z = (float*)d_out;

    char* ws = (char*)d_ws;
    u16* x_bf   = (u16*)(ws);                  // 18432*768*2   = 28,311,552
    u16* qkv_bf = (u16*)(ws + 28311552);       // 18432*2304*2  = 84,934,656
    u16* vT     = (u16*)(ws + 113246208);      // 32*12*64*576*2= 28,311,552
    u16* wqkvT  = (u16*)(ws + 141557760);      // per-layer 3,538,944 (x12 if batched)
    // batched path needs 141557760 + 42467328 + 14155776 = 198,180,864 bytes
    bool batched = ws_size >= 198180864ull;
    u16* wmlpT  = batched ? (u16*)(ws + 184025088) : (u16*)(ws + 145096704);

    hipMemcpyAsync(z, z_in, (size_t)BN_ROWS * DMODEL * sizeof(float),
                   hipMemcpyDeviceToDevice, stream);

    if (batched) {   // all 12 layers' weight transposes in 2 launches, up front
        transpose_cast_kernel<<<dim3(QKV_N / 64, DMODEL / 64, L_LAYERS), 256, 0, stream>>>(
            Wqkv, wqkvT, DMODEL, QKV_N);
        transpose_cast_kernel<<<dim3(DMODEL / 64, DMODEL / 64, L_LAYERS), 256, 0, stream>>>(
            Wmlp, wmlpT, DMODEL, DMODEL);
    }

    for (int l = 0; l < L_LAYERS; ++l) {
        u16* wq = batched ? wqkvT + (size_t)l * DMODEL * QKV_N  : wqkvT;
        u16* wm = batched ? wmlpT + (size_t)l * DMODEL * DMODEL : wmlpT;
        if (!batched) {
            transpose_cast_kernel<<<dim3(QKV_N / 64, DMODEL / 64, 1), 256, 0, stream>>>(
                Wqkv + (size_t)l * DMODEL * QKV_N, wq, DMODEL, QKV_N);
            transpose_cast_kernel<<<dim3(DMODEL / 64, DMODEL / 64, 1), 256, 0, stream>>>(
                Wmlp + (size_t)l * DMODEL * DMODEL, wm, DMODEL, DMODEL);
        }

        ln_kernel<<<BN_ROWS / 4, 256, 0, stream>>>(z, ln1_g + l * DMODEL, ln1_b + l * DMODEL, x_bf);

        gemm_kernel<0><<<dim3(QKV_N / 256, BN_ROWS / 128), 256, 0, stream>>>(
            x_bf, wq, BN_ROWS, QKV_N, DMODEL, qkv_bf, nullptr, nullptr);

        vtrans_kernel<<<dim3(NTOK / 64, NHEAD, BATCH), 256, 0, stream>>>(qkv_bf, vT);

        attn_kernel<<<3 * NHEAD * BATCH, 768, 0, stream>>>(qkv_bf, vT, z);

        ln_kernel<<<BN_ROWS / 4, 256, 0, stream>>>(z, ln2_g + l * DMODEL, ln2_b + l * DMODEL, x_bf);

        gemm_kernel<1><<<dim3(DMODEL / 256, BN_ROWS / 128), 256, 0, stream>>>(
            x_bf, wm, BN_ROWS, DMODEL, DMODEL, nullptr, bmlp + l * DMODEL, z);
    }
}

// Round 20
// 2750.334 us; speedup vs baseline: 1.3466x; 1.3466x over previous
//
#include <hip/hip_runtime.h>
#include <hip/hip_bf16.h>

typedef unsigned short u16;
typedef short bfrag __attribute__((ext_vector_type(8)));   // 8 bf16 operand frag
typedef float f32x4 __attribute__((ext_vector_type(4)));   // MFMA accumulator

#define L_LAYERS 12
#define BATCH 32
#define NTOK 576
#define DMODEL 768
#define NHEAD 12
#define DHEAD 64
#define BN_ROWS (BATCH * NTOK)   // 18432
#define QKV_N (3 * DMODEL)       // 2304

__device__ __forceinline__ u16 f2bf(float f) {
    __hip_bfloat16 h = __float2bfloat16(f);   // HW RNE convert
    return *reinterpret_cast<u16*>(&h);
}

__device__ __forceinline__ void gload_lds16(const void* g, void* l) {
    __builtin_amdgcn_global_load_lds(
        (const __attribute__((address_space(1))) void*)g,
        (__attribute__((address_space(3))) void*)l, 16, 0, 0);
}

// ---------------- transpose + fp32->bf16 cast: src[R][C] -> dst[C][R], per-layer via z ----------------
__global__ __launch_bounds__(256) void transpose_cast_kernel(
        const float* __restrict__ src, u16* __restrict__ dst, int R, int C) {
    __shared__ u16 tile[64][65];
    size_t loff = (size_t)blockIdx.z * R * C;
    src += loff;
    dst += loff;
    int c0 = blockIdx.x * 64, r0 = blockIdx.y * 64;
    int tid = threadIdx.x;
    for (int i = tid; i < 4096; i += 256) {
        int rr = i >> 6, cc = i & 63;
        tile[rr][cc] = f2bf(src[(size_t)(r0 + rr) * C + c0 + cc]);
    }
    __syncthreads();
    for (int i = tid; i < 4096; i += 256) {
        int cc = i >> 6, rr = i & 63;
        dst[(size_t)(c0 + cc) * R + r0 + rr] = tile[rr][cc];
    }
}

// ---------------- LayerNorm: fp32 z row -> bf16 out row (one row per wave) ----------------
__global__ __launch_bounds__(256) void ln_kernel(
        const float* __restrict__ z, const float* __restrict__ g,
        const float* __restrict__ b, u16* __restrict__ out) {
    int w = threadIdx.x >> 6, lane = threadIdx.x & 63;
    int row = blockIdx.x * 4 + w;
    const float* zr = z + (size_t)row * DMODEL;
    float4 v[3];
    float sum = 0.f, sq = 0.f;
#pragma unroll
    for (int c = 0; c < 3; ++c) {
        v[c] = *(const float4*)(zr + c * 256 + lane * 4);
        sum += v[c].x + v[c].y + v[c].z + v[c].w;
        sq  += v[c].x * v[c].x + v[c].y * v[c].y + v[c].z * v[c].z + v[c].w * v[c].w;
    }
#pragma unroll
    for (int m = 1; m < 64; m <<= 1) {
        sum += __shfl_xor(sum, m);
        sq  += __shfl_xor(sq, m);
    }
    float mean = sum * (1.0f / DMODEL);
    float var  = sq * (1.0f / DMODEL) - mean * mean;
    float inv  = 1.0f / sqrtf(var + 1e-5f);
    u16* orow = out + (size_t)row * DMODEL;
#pragma unroll
    for (int c = 0; c < 3; ++c) {
        int col = c * 256 + lane * 4;
        float4 gg = *(const float4*)(g + col);
        float4 bb = *(const float4*)(b + col);
        ushort4 u;
        u.x = f2bf((v[c].x - mean) * inv * gg.x + bb.x);
        u.y = f2bf((v[c].y - mean) * inv * gg.y + bb.y);
        u.z = f2bf((v[c].z - mean) * inv * gg.z + bb.z);
        u.w = f2bf((v[c].w - mean) * inv * gg.w + bb.w);
        *(ushort4*)(orow + col) = u;
    }
}

// ---------------- bf16 MFMA GEMM: 128(M)x256(N) tile, 512 threads (8 waves 2x4) ----------------
// T4 deep pipeline: 3 LDS buffers (72KB), loads issued 2 K-steps ahead, counted
// s_waitcnt vmcnt(3) + ONE raw s_barrier per K-step (no vmcnt(0) drain in loop).
// T2 XOR slot-swizzle (bank conflicts == 0, round-17 verified). T5 setprio around
// the MFMA cluster. XCD-swizzled grid. Correctness ledger:
//  - writes at iter t target buf[(t+2)%3] == buffer last READ at t-1; those ds_reads
//    retired before t-1's barrier (lgkm-before-MFMA, MFMA-before-barrier).
//  - vmcnt(3) before barrier leaves only this iter's 3 loads outstanding => t+1's
//    buffer fully landed for ALL waves after the barrier.
//  - empty asm memory fences + sched_barrier(0) pin loads around the raw barrier.
// R19 lesson: 4-wave/acc[8][4] geometry -> VGPR 136, occupancy 9.5%, -45% — keep 8 waves.
// NOTE: plain __launch_bounds__(512) — min-waves clause spills accumulators (R10).
template<int MODE>
__global__ __launch_bounds__(512) void gemm_kernel(
        const u16* __restrict__ A, const u16* __restrict__ Bt,
        int M, int N, int K,
        u16* __restrict__ obf, const float* __restrict__ bias, float* __restrict__ zres) {
    __shared__ __attribute__((aligned(16))) u16 As[3][128 * 32];   // 8KB per buf
    __shared__ __attribute__((aligned(16))) u16 Bs[3][256 * 32];   // 16KB per buf
    int tid = threadIdx.x;
    int lane = tid & 63, w = tid >> 6;        // w 0..7
    int wr = w >> 2, wc = w & 3;
    int r = lane & 15, gq = lane >> 4;

    // XCD-aware bijective swizzle (nwg % 8 == 0 for all our launches)
    int nwg = gridDim.x * gridDim.y;
    int lin = blockIdx.y * gridDim.x + blockIdx.x;
    int swz = (lin & 7) * (nwg >> 3) + (lin >> 3);
    int bx = swz % gridDim.x, by = swz / gridDim.x;
    int m0 = by * 128, n0 = bx * 256;

    int srow = tid >> 2;          // 0..127 (4 lanes per row)
    // T2 swizzle, stage side: lane's k-segment = slot ^ ((srow>>1)&3)
    int sseg = (((tid & 3) ^ ((tid >> 3) & 3))) * 8;     // u16 col offset (pre-swizzled)
    const u16* aSrc  = A  + (size_t)(m0 + srow) * K + sseg;
    const u16* bSrc  = Bt + (size_t)(n0 + srow) * K + sseg;
    const u16* bSrc2 = Bt + (size_t)(n0 + 128 + srow) * K + sseg;

    // T2 swizzle, read side
    int rslot = (gq ^ ((r >> 1) & 3)) * 8;               // u16 offset within row

    f32x4 acc[4][4];
#pragma unroll
    for (int mi = 0; mi < 4; ++mi)
#pragma unroll
        for (int ni = 0; ni < 4; ++ni)
            acc[mi][ni] = (f32x4){0.f, 0.f, 0.f, 0.f};

    // stage K-step kt into buffer sb (3 gload_lds per thread, LDS dest wave-linear)
    auto stage = [&](int kt, int sb) {
        int o = kt << 5;
        gload_lds16(aSrc + o,  &As[sb][w * 512]);
        gload_lds16(bSrc + o,  &Bs[sb][w * 512]);
        gload_lds16(bSrc2 + o, &Bs[sb][4096 + w * 512]);
    };

    int T = K >> 5;
    // prologue: issue t=0 and t=1; wait t=0 landed (t=1's 3 may stay in flight)
    stage(0, 0);
    stage(1, 1);
    asm volatile("s_waitcnt vmcnt(3)" ::: "memory");
    __builtin_amdgcn_s_barrier();
    asm volatile("" ::: "memory");

    int cb = 0, sb = 2;   // read buffer, stage buffer (rotating mod 3)
    for (int t = 0; t < T; ++t) {
        bfrag af[4], bfv[4];
#pragma unroll
        for (int mi = 0; mi < 4; ++mi)
            af[mi] = *(const bfrag*)(&As[cb][(wr * 64 + mi * 16 + r) * 32 + rslot]);
#pragma unroll
        for (int ni = 0; ni < 4; ++ni)
            bfv[ni] = *(const bfrag*)(&Bs[cb][(wc * 64 + ni * 16 + r) * 32 + rslot]);

        bool more = (t + 2) < T;
        if (more) stage(t + 2, sb);

        __builtin_amdgcn_s_setprio(1);
#pragma unroll
        for (int mi = 0; mi < 4; ++mi)
#pragma unroll
            for (int ni = 0; ni < 4; ++ni)
                acc[mi][ni] = __builtin_amdgcn_mfma_f32_16x16x32_bf16(af[mi], bfv[ni], acc[mi][ni], 0, 0, 0);
        __builtin_amdgcn_s_setprio(0);

        if (more) asm volatile("s_waitcnt vmcnt(3)" ::: "memory");
        else      asm volatile("s_waitcnt vmcnt(0)" ::: "memory");
        asm volatile("" ::: "memory");
        __builtin_amdgcn_s_barrier();          // publish buf for t+1
        __builtin_amdgcn_sched_barrier(0);
        asm volatile("" ::: "memory");

        cb = (cb == 2) ? 0 : cb + 1;
        sb = (sb == 2) ? 0 : sb + 1;
    }

#pragma unroll
    for (int mi = 0; mi < 4; ++mi) {
#pragma unroll
        for (int ni = 0; ni < 4; ++ni) {
            int col = n0 + wc * 64 + ni * 16 + r;
#pragma unroll
            for (int j = 0; j < 4; ++j) {
                int row = m0 + wr * 64 + mi * 16 + gq * 4 + j;
                if (MODE == 0) {
                    obf[(size_t)row * N + col] = f2bf(acc[mi][ni][j]);
                } else {
                    zres[(size_t)row * N + col] += acc[mi][ni][j] + bias[col];
                }
            }
        }
    }
}

// ---------------- V transpose: qkv V-part [key][dh] -> vT [b][h][dh][key] ----------------
__global__ __launch_bounds__(256) void vtrans_kernel(
        const u16* __restrict__ qkv, u16* __restrict__ vT) {
    __shared__ u16 tile[64][65];
    int kt = blockIdx.x, h = blockIdx.y, b = blockIdx.z;
    int tid = threadIdx.x;
    int k0 = kt * 64;
    const u16* src = qkv + (size_t)(b * NTOK + k0) * QKV_N + h * 192 + 128;
    for (int i = tid; i < 4096; i += 256) {
        int rr = i >> 6, cc = i & 63;
        tile[rr][cc] = src[(size_t)rr * QKV_N + cc];
    }
    __syncthreads();
    u16* dst = vT + (size_t)(b * NHEAD + h) * DHEAD * NTOK + k0;
    for (int i = tid; i < 4096; i += 256) {
        int dh = i >> 6, kk = i & 63;
        dst[(size_t)dh * NTOK + kk] = tile[kk][dh];
    }
}

// ---------------- flash attention: 12 waves x 16 q-rows (QBLK=192, 576=3x192 exact).
//   K/V staged via coalesced global_load_lds (dbuf, XOR slot-swizzled source);
//   swapped-operand QK^T, in-lane softmax (max3 tree) with T13 defer-max, cvt_pk P2,
//   MFMA ones-row denominator, T5 setprio, ONE barrier per chunk.
//   1152 blocks = 8 XCDs x 48 groups x 3 q-tiles (bijective).
#define KC 64
#define NCHUNK 9
#define SM_C 0.18033688f   // 0.125 * log2(e)
#define DEFER_THR 44.3614f // 8 / SM_C: skip rescale while P bounded by 2^8
__global__ __launch_bounds__(768) void attn_kernel(
        const u16* __restrict__ qkv, const u16* __restrict__ vT, float* __restrict__ z) {
    __shared__ __attribute__((aligned(16))) u16 Kst[2][KC * 64];        // [key][dh-slot]  16KB
    __shared__ __attribute__((aligned(16))) u16 Vst[2][DHEAD * KC];     // [dh][key-slot]  16KB
    __shared__ __attribute__((aligned(16))) unsigned P2[12][16][36];    // [wave][q][keypair+pad] 27KB
    int i = blockIdx.x;
    int slot = i >> 3;            // 0..143
    int qt = slot % 3;
    int g = (i & 7) * 48 + slot / 3;
    int h = g % NHEAD, b = g / NHEAD;
    int tid = threadIdx.x, lane = tid & 63, w = tid >> 6;   // w 0..11
    int r = lane & 15, gq = lane >> 4;
    int q0 = qt * 192 + w * 16;

    // Q fragments (B-operand of swapped QK^T): lane holds Q[q=q0+r][dh=gq*8..+7]
    const u16* qbase = qkv + (size_t)(b * NTOK + q0 + r) * QKV_N + h * 192;
    bfrag qf0 = *(const bfrag*)(qbase + gq * 8);
    bfrag qf1 = *(const bfrag*)(qbase + 32 + gq * 8);

    // staging lane geometry: each call covers 8 rows (8 lanes x 16B per row)
    int lrow = lane >> 3;                    // 0..7
    int sslot = (lane & 7) ^ lrow;           // XOR swizzle (row&7 == lrow)
    const u16* ksrc = qkv + (size_t)(b * NTOK + lrow) * QKV_N + h * 192 + 64 + sslot * 8;
    const u16* vsrc = vT + ((size_t)(b * NHEAD + h) * DHEAD + lrow) * NTOK + sslot * 8;

    float* zb = z + (size_t)(b * NTOK + q0) * DMODEL + h * DHEAD;

    bfrag ones;
#pragma unroll
    for (int q = 0; q < 8; ++q) ones[q] = (short)0x3F80;   // bf16 1.0 x8

    float mrun = -1e30f;
    f32x4 o[4], lacc;
#pragma unroll
    for (int ni = 0; ni < 4; ++ni) o[ni] = (f32x4){0.f, 0.f, 0.f, 0.f};
    lacc = (f32x4){0.f, 0.f, 0.f, 0.f};

    // stage chunk c into buffer bf: 16 segments (K rows = c2 0..7, V rows = c2 8..15),
    // wave w takes c2 = w and w+12 (<16); wave-uniform branch
    auto stage = [&](int c, int bf) {
#pragma unroll
        for (int k = 0; k < 2; ++k) {
            int c2 = w + 12 * k;
            if (c2 < 16) {
                if (c2 < 8)
                    gload_lds16(ksrc + (size_t)(c * KC + c2 * 8) * QKV_N,
                                &Kst[bf][(c2 * 8) * 64]);
                else
                    gload_lds16(vsrc + (size_t)((c2 - 8) * 8) * NTOK + c * KC,
                                &Vst[bf][((c2 - 8) * 8) * 64]);
            }
        }
    };

    // prologue: stage chunk 0 into buf 0
    stage(0, 0);
    __syncthreads();

#pragma unroll
    for (int c = 0; c < NCHUNK; ++c) {
        int cur = c & 1;
        if (c + 1 < NCHUNK) stage(c + 1, cur ^ 1);

        // S^T chunk = (K @ Q^T): s[kc][j] = S[key = c*64+kc*16+gq*4+j][q = q0+r]
        // K frags from swizzled LDS: row kc*16+r, want slot gq -> stored gq^(r&7).
        f32x4 s[4];
#pragma unroll
        for (int kc = 0; kc < 4; ++kc) s[kc] = (f32x4){0.f, 0.f, 0.f, 0.f};
        int s0 = gq ^ (r & 7);
        __builtin_amdgcn_s_setprio(1);
#pragma unroll
        for (int kc = 0; kc < 4; ++kc) {
            const u16* kf = &Kst[cur][(kc * 16 + r) * 64];
            bfrag k0 = *(const bfrag*)(kf + s0 * 8);
            bfrag k1 = *(const bfrag*)(kf + (s0 ^ 4) * 8);
            s[kc] = __builtin_amdgcn_mfma_f32_16x16x32_bf16(k0, qf0, s[kc], 0, 0, 0);
            s[kc] = __builtin_amdgcn_mfma_f32_16x16x32_bf16(k1, qf1, s[kc], 0, 0, 0);
        }
        __builtin_amdgcn_s_setprio(0);

        // chunk max for q = q0+r: max3-friendly tree over 16 + 2 cross-gq shfl
        float m0a = fmaxf(fmaxf(s[0][0], s[0][1]), s[0][2]);
        float m0b = fmaxf(fmaxf(s[0][3], s[1][0]), s[1][1]);
        float m0c = fmaxf(fmaxf(s[1][2], s[1][3]), s[2][0]);
        float m0d = fmaxf(fmaxf(s[2][1], s[2][2]), s[2][3]);
        float m0e = fmaxf(fmaxf(s[3][0], s[3][1]), s[3][2]);
        float cm  = fmaxf(fmaxf(m0a, m0b), fmaxf(fmaxf(m0c, m0d), fmaxf(m0e, s[3][3])));
        cm = fmaxf(cm, __shfl_xor(cm, 16));
        cm = fmaxf(cm, __shfl_xor(cm, 32));

        // T13 defer-max: keep old max while growth <= 8/SM_C (P bounded by 2^8; exact
        // after final O/l normalize). Rescale only on real growth.
        bool need = !__all(cm <= mrun + DEFER_THR);
        float nm = need ? fmaxf(mrun, cm) : mrun;
        float nmC = nm * SM_C;
#pragma unroll
        for (int kc = 0; kc < 4; ++kc)
#pragma unroll
            for (int j = 0; j < 4; ++j)
                s[kc][j] = exp2f(s[kc][j] * SM_C - nmC);
        if (need) {
            float fac = exp2f((mrun - nm) * SM_C);
            mrun = nm;
#pragma unroll
            for (int ni = 0; ni < 4; ++ni)
#pragma unroll
                for (int j = 0; j < 4; ++j) o[ni][j] *= fac;
#pragma unroll
            for (int j = 0; j < 4; ++j) lacc[j] *= fac;
        }

        // pack P to bf16 pairs -> per-wave LDS P2 (P row per q, contiguous keys)
#pragma unroll
        for (int kc = 0; kc < 4; ++kc)
#pragma unroll
            for (int X = 0; X < 2; ++X) {
                unsigned pk;
                asm("v_cvt_pk_bf16_f32 %0, %1, %2" : "=v"(pk) : "v"(s[kc][2 * X]), "v"(s[kc][2 * X + 1]));
                P2[w][r][kc * 8 + gq * 2 + X] = pk;
            }

        // O^T += V^T @ P^T ; denominator l += 1^T @ P^T (ones-row MFMA replaces the
        // VALU sum chain — l computed from the same bf16 P that PV consumes).
        __builtin_amdgcn_s_setprio(1);
#pragma unroll
        for (int ks = 0; ks < 2; ++ks) {
            bfrag pf = *(const bfrag*)(&P2[w][r][ks * 16 + gq * 4]);
            int vs = (ks * 4 + gq) ^ (r & 7);
#pragma unroll
            for (int ni = 0; ni < 4; ++ni) {
                bfrag vf = *(const bfrag*)(&Vst[cur][(ni * 16 + r) * 64 + vs * 8]);
                o[ni] = __builtin_amdgcn_mfma_f32_16x16x32_bf16(vf, pf, o[ni], 0, 0, 0);
            }
            lacc = __builtin_amdgcn_mfma_f32_16x16x32_bf16(ones, pf, lacc, 0, 0, 0);
        }
        __builtin_amdgcn_s_setprio(0);
        __syncthreads();   // all waves done with Kst/Vst[cur]; prefetch landed
    }

    // z += O / l : lane (gq,r) holds O[q=r][dh = ni*16 + gq*4 + j]  (float4 RMW, disjoint)
    float inv = 1.0f / lacc[0];
#pragma unroll
    for (int ni = 0; ni < 4; ++ni) {
        float* p = zb + (size_t)r * DMODEL + ni * 16 + gq * 4;
        float4 t = *(float4*)p;
        t.x += o[ni][0] * inv;
        t.y += o[ni][1] * inv;
        t.z += o[ni][2] * inv;
        t.w += o[ni][3] * inv;
        *(float4*)p = t;
    }
}

extern "C" void kernel_launch(void* const* d_in, const int* in_sizes, int n_in,
                              void* d_out, int out_size, void* d_ws, size_t ws_size,
                              hipStream_t stream) {
    const float* z_in  = (const float*)d_in[0];
    const float* Wqkv  = (const float*)d_in[1];
    const float* ln1_g = (const float*)d_in[2];
    const float* ln1_b = (const float*)d_in[3];
    const float* Wmlp  = (const float*)d_in[4];
    const float* bmlp  = (const float*)d_in[5];
    const float* ln2_g = (const float*)d_in[6];
    const float* ln2_b = (const float*)d_in[7];
    float* z = (float*)d_out;

    char* ws = (char*)d_ws;
    u16* x_bf   = (u16*)(ws);                  // 18432*768*2   = 28,311,552
    u16* qkv_bf = (u16*)(ws + 28311552);       // 18432*2304*2  = 84,934,656
    u16* vT     = (u16*)(ws + 113246208);      // 32*12*64*576*2= 28,311,552
    u16* wqkvT  = (u16*)(ws + 141557760);      // per-layer 3,538,944 (x12 if batched)
    // batched path needs 141557760 + 42467328 + 14155776 = 198,180,864 bytes
    bool batched = ws_size >= 198180864ull;
    u16* wmlpT  = batched ? (u16*)(ws + 184025088) : (u16*)(ws + 145096704);

    hipMemcpyAsync(z, z_in, (size_t)BN_ROWS * DMODEL * sizeof(float),
                   hipMemcpyDeviceToDevice, stream);

    if (batched) {   // all 12 layers' weight transposes in 2 launches, up front
        transpose_cast_kernel<<<dim3(QKV_N / 64, DMODEL / 64, L_LAYERS), 256, 0, stream>>>(
            Wqkv, wqkvT, DMODEL, QKV_N);
        transpose_cast_kernel<<<dim3(DMODEL / 64, DMODEL / 64, L_LAYERS), 256, 0, stream>>>(
            Wmlp, wmlpT, DMODEL, DMODEL);
    }

    for (int l = 0; l < L_LAYERS; ++l) {
        u16* wq = batched ? wqkvT + (size_t)l * DMODEL * QKV_N  : wqkvT;
        u16* wm = batched ? wmlpT + (size_t)l * DMODEL * DMODEL : wmlpT;
        if (!batched) {
            transpose_cast_kernel<<<dim3(QKV_N / 64, DMODEL / 64, 1), 256, 0, stream>>>(
                Wqkv + (size_t)l * DMODEL * QKV_N, wq, DMODEL, QKV_N);
            transpose_cast_kernel<<<dim3(DMODEL / 64, DMODEL / 64, 1), 256, 0, stream>>>(
                Wmlp + (size_t)l * DMODEL * DMODEL, wm, DMODEL, DMODEL);
        }

        ln_kernel<<<BN_ROWS / 4, 256, 0, stream>>>(z, ln1_g + l * DMODEL, ln1_b + l * DMODEL, x_bf);

        gemm_kernel<0><<<dim3(QKV_N / 256, BN_ROWS / 128), 512, 0, stream>>>(
            x_bf, wq, BN_ROWS, QKV_N, DMODEL, qkv_bf, nullptr, nullptr);

        vtrans_kernel<<<dim3(NTOK / 64, NHEAD, BATCH), 256, 0, stream>>>(qkv_bf, vT);

        attn_kernel<<<3 * NHEAD * BATCH, 768, 0, stream>>>(qkv_bf, vT, z);

        ln_kernel<<<BN_ROWS / 4, 256, 0, stream>>>(z, ln2_g + l * DMODEL, ln2_b + l * DMODEL, x_bf);

        gemm_kernel<1><<<dim3(DMODEL / 256, BN_ROWS / 128), 512, 0, stream>>>(
            x_bf, wm, BN_ROWS, DMODEL, DMODEL, nullptr, bmlp + l * DMODEL, z);
    }
}